// Round 10
// baseline (102.986 us; speedup 1.0000x reference)
//
#include <hip/hip_runtime.h>

// AugmentShallow, round 10: zero-barrier streaming k_out + R4-proven k_mlp.
//
// History: every LDS-staged gather->barrier->GEMM variant = 50-57us with all
// pipes idle (latency-bound); big tiles, max TLP, NT stores, packed weights
// all failed to move it. This round tests the phase-convoy theory: k_out_s
// has NO LDS, NO barriers — each wave gathers its 32 points into registers
// (96 independent loads), builds MFMA B-fragments in-register (bit-identical
// to the proven LDS path), and streams 8 W2 oc-strips (split in-register).
// Back to 2 graph nodes (prep/planes never measured a win; R4=77us best).
//
// ws: [0,16Mi) t f16 [65536][128].

typedef __attribute__((ext_vector_type(8))) _Float16 h8;
typedef __attribute__((ext_vector_type(4))) _Float16 h4;
typedef __attribute__((ext_vector_type(4))) float    f4;

#define MFMA_H __builtin_amdgcn_mfma_f32_16x16x32_f16

#define LO_SCALE_INV 2.44140625e-4f   // 2^-12

__device__ __forceinline__ void splitW8(const float* __restrict__ p, h8& hi, h8& lo) {
    const float4 a = *(const float4*)p;
    const float4 b = *(const float4*)(p + 4);
    const float v[8] = {a.x, a.y, a.z, a.w, b.x, b.y, b.z, b.w};
#pragma unroll
    for (int j = 0; j < 8; ++j) {
        const _Float16 h = (_Float16)v[j];
        hi[j] = h;
        lo[j] = (_Float16)((v[j] - (float)h) * 4096.f);
    }
}

// ---------------------------------------------------------------------------
// Kernel 1: point MLP (R4 verbatim — proven absmax 9.766e-4).
// 1024 blocks x 256 thr, 64 points per block; wave w owns oc strip
// [32w,32w+32); weights split in-register; h ping-pong in LDS.
// ---------------------------------------------------------------------------
__global__ __launch_bounds__(256) void k_mlp(
    const float* __restrict__ x,
    const float* __restrict__ W1, const float* __restrict__ b1,
    const float* __restrict__ Wc0, const float* __restrict__ bc0,
    const float* __restrict__ Wc1, const float* __restrict__ bc1,
    _Float16* __restrict__ t)
{
    __shared__ __align__(16) _Float16 hA[64 * 128];   // 16 KiB
    __shared__ __align__(16) _Float16 hB[64 * 128];   // 16 KiB

    const int tid = threadIdx.x;
    const int bid = blockIdx.x;
    const int lb  = (bid & 7) * 128 + (bid >> 3);   // batch = lb>>7 = bid&7 (XCD pin)
    const long pblk = (long)lb * 64;

    // ---- layer 1 (VALU, K=3, no relu): thread = (pt, 32-ch quarter) ----
    {
        const int pt  = tid >> 2;
        const int q4  = tid & 3;
        const int ch0 = q4 * 32;
        const float* xp = x + (pblk + pt) * 3;
        const float x0 = xp[0], x1 = xp[1], x2 = xp[2];
        const int p7 = pt & 7;
#pragma unroll
        for (int q = 0; q < 4; ++q) {
            h8 hv;
#pragma unroll
            for (int j = 0; j < 8; ++j) {
                const int c = ch0 + q * 8 + j;
                float v = b1[c];
                v = fmaf(W1[c * 3 + 0], x0, v);
                v = fmaf(W1[c * 3 + 1], x1, v);
                v = fmaf(W1[c * 3 + 2], x2, v);
                hv[j] = (_Float16)v;
            }
            const int chunk = q4 * 4 + q;
            *(h8*)&hA[pt * 128 + ((chunk ^ p7) << 3)] = hv;
        }
    }
    __syncthreads();

    const int lane = tid & 63;
    const int w  = tid >> 6;
    const int fr = lane & 15;
    const int g  = lane >> 4;
    const int ocb = w * 32;

#pragma unroll
    for (int layer = 0; layer < 2; ++layer) {
        const float* W  = layer ? Wc1 : Wc0;
        const float* bp = layer ? bc1 : bc0;

        h8 Ah[2][4], Al[2][4];
#pragma unroll
        for (int T = 0; T < 2; ++T)
#pragma unroll
            for (int c = 0; c < 4; ++c)
                splitW8(W + (long)(ocb + T * 16 + fr) * 128 + c * 32 + g * 8,
                        Ah[T][c], Al[T][c]);

        f4 bias[2];
#pragma unroll
        for (int T = 0; T < 2; ++T) {
            const float4 bv = *(const float4*)(bp + ocb + T * 16 + g * 4);
            bias[T] = (f4){bv.x, bv.y, bv.z, bv.w};
        }

        const _Float16* hin = layer ? hB : hA;
        const f4 zf = {0.f, 0.f, 0.f, 0.f};

#pragma unroll 2
        for (int p = 0; p < 4; ++p) {
            const int pt = p * 16 + fr;
            const int p7 = pt & 7;
            h8 B[4];
#pragma unroll
            for (int c = 0; c < 4; ++c)
                B[c] = *(const h8*)&hin[pt * 128 + (((4 * c + g) ^ p7) << 3)];

            f4 ahi[2] = {bias[0], bias[1]};
            f4 alo[2] = {zf, zf};
#pragma unroll
            for (int c = 0; c < 4; ++c) {
#pragma unroll
                for (int T = 0; T < 2; ++T) {
                    ahi[T] = MFMA_H(Ah[T][c], B[c], ahi[T], 0, 0, 0);
                    alo[T] = MFMA_H(Al[T][c], B[c], alo[T], 0, 0, 0);
                }
            }
#pragma unroll
            for (int T = 0; T < 2; ++T) {
                const int ocoff = ocb + T * 16 + g * 4;
                h4 o;
#pragma unroll
                for (int r = 0; r < 4; ++r)
                    o[r] = (_Float16)fmaxf(fmaf(alo[T][r], LO_SCALE_INV, ahi[T][r]), 0.f);
                if (layer == 0) {
                    const int sidx = pt * 128 + (((ocoff >> 3) ^ p7) << 3) + (ocoff & 7);
                    *(h4*)&hB[sidx] = o;
                } else {
                    *(h4*)&t[(pblk + pt) * 128 + ocoff] = o;
                }
            }
        }
        if (layer == 0) __syncthreads();
    }
}

// ---------------------------------------------------------------------------
// Kernel 2: streaming gather + W2 GEMM. 512 blocks x 256 thr. NO LDS, NO
// barriers. Wave owns 32 pts (2 p-tiles): gather 96 independent 16B loads
// -> fp32 accs -> in-register f16 B-fragments (same rounding/k-map as the
// proven LDS path) -> 8 W2 oc-strips split in-register -> direct stores.
// ---------------------------------------------------------------------------
__global__ __launch_bounds__(256) void k_out_s(
    const int* __restrict__ knn,
    const _Float16* __restrict__ t,
    const float* __restrict__ W2, const float* __restrict__ b2,
    float* __restrict__ out)
{
    const int tid = threadIdx.x;
    const int bid = blockIdx.x;
    const int lb  = (bid & 7) * 64 + (bid >> 3);    // batch = lb>>6 = bid&7
    const long pbase = (long)lb * 128;
    const long bbase = (long)(bid & 7) * 8192;      // batch row base in t

    const int lane = tid & 63;
    const int w  = tid >> 6;
    const int fr = lane & 15;
    const int g  = lane >> 4;
    const long base = pbase + w * 32;               // this wave's 32 points

    // ---- gather-mean straight into registers (both p-tiles) ----
    int idx[2][12];
#pragma unroll
    for (int p2 = 0; p2 < 2; ++p2) {
        const int* ip = knn + (base + p2 * 16 + fr) * 12;
        *(int4*)&idx[p2][0] = *(const int4*)(ip + 0);
        *(int4*)&idx[p2][4] = *(const int4*)(ip + 4);
        *(int4*)&idx[p2][8] = *(const int4*)(ip + 8);
    }

    float acc[2][32];
#pragma unroll
    for (int p2 = 0; p2 < 2; ++p2)
#pragma unroll
        for (int c = 0; c < 32; ++c) acc[p2][c] = 0.f;

#pragma unroll
    for (int p2 = 0; p2 < 2; ++p2) {
#pragma unroll
        for (int k = 0; k < 12; ++k) {
            const _Float16* tp = t + (bbase + idx[p2][k]) * 128 + g * 8;
#pragma unroll
            for (int c = 0; c < 4; ++c) {
                const h8 v = *(const h8*)(tp + c * 32);
#pragma unroll
                for (int j = 0; j < 8; ++j) acc[p2][c * 8 + j] += (float)v[j];
            }
        }
    }

    // m -> f16 B-fragments (identical rounding + k-map as proven LDS path)
    h8 B[2][4];
#pragma unroll
    for (int p2 = 0; p2 < 2; ++p2)
#pragma unroll
        for (int c = 0; c < 4; ++c)
#pragma unroll
            for (int j = 0; j < 8; ++j)
                B[p2][c][j] = (_Float16)(acc[p2][c * 8 + j] * (1.f / 12.f));

    // ---- 8 oc-strips of W2: split in-register, MFMA, store ----
#pragma unroll 1
    for (int st = 0; st < 8; ++st) {
        const int ocb = st * 32;

        h8 Ah[2][4], Al[2][4];
#pragma unroll
        for (int T = 0; T < 2; ++T)
#pragma unroll
            for (int c = 0; c < 4; ++c)
                splitW8(W2 + (long)(ocb + T * 16 + fr) * 128 + c * 32 + g * 8,
                        Ah[T][c], Al[T][c]);

        f4 bv[2];
#pragma unroll
        for (int T = 0; T < 2; ++T) {
            const float4 q = *(const float4*)(b2 + ocb + T * 16 + g * 4);
            bv[T] = (f4){q.x, q.y, q.z, q.w};
        }

#pragma unroll
        for (int p2 = 0; p2 < 2; ++p2) {
            f4 ahi[2] = {bv[0], bv[1]};
            f4 alo[2] = {{0.f, 0.f, 0.f, 0.f}, {0.f, 0.f, 0.f, 0.f}};
#pragma unroll
            for (int c = 0; c < 4; ++c)
#pragma unroll
                for (int T = 0; T < 2; ++T) {
                    ahi[T] = MFMA_H(Ah[T][c], B[p2][c], ahi[T], 0, 0, 0);
                    alo[T] = MFMA_H(Al[T][c], B[p2][c], alo[T], 0, 0, 0);
                }
#pragma unroll
            for (int T = 0; T < 2; ++T) {
                float4 o;
                o.x = fmaf(alo[T][0], LO_SCALE_INV, ahi[T][0]);
                o.y = fmaf(alo[T][1], LO_SCALE_INV, ahi[T][1]);
                o.z = fmaf(alo[T][2], LO_SCALE_INV, ahi[T][2]);
                o.w = fmaf(alo[T][3], LO_SCALE_INV, ahi[T][3]);
                *(float4*)&out[(base + p2 * 16 + fr) * 256 + ocb + T * 16 + g * 4] = o;
            }
        }
    }
}

// ---------------------------------------------------------------------------

extern "C" void kernel_launch(void* const* d_in, const int* in_sizes, int n_in,
                              void* d_out, int out_size, void* d_ws, size_t ws_size,
                              hipStream_t stream)
{
    const float* x   = (const float*)d_in[0];
    const int*   knn = (const int*)d_in[1];
    const float* W1  = (const float*)d_in[2];
    const float* b1  = (const float*)d_in[3];
    const float* Wc0 = (const float*)d_in[4];
    const float* bc0 = (const float*)d_in[5];
    const float* Wc1 = (const float*)d_in[6];
    const float* bc1 = (const float*)d_in[7];
    const float* W2  = (const float*)d_in[8];
    const float* b2  = (const float*)d_in[9];
    float* out = (float*)d_out;

    _Float16* t = (_Float16*)d_ws;   // 16 MiB

    k_mlp  <<<dim3(1024), dim3(256), 0, stream>>>(x, W1, b1, Wc0, bc0, Wc1, bc1, t);
    k_out_s<<<dim3(512),  dim3(256), 0, stream>>>(knn, t, W2, b2, out);
}